// Round 15
// baseline (390.436 us; speedup 1.0000x reference)
//
#include <hip/hip_runtime.h>
#include <stdint.h>

#define B_ 64
#define T_ 4096
#define H_ 256
#define U_ 256

typedef float f32x4 __attribute__((ext_vector_type(4)));
typedef short short8 __attribute__((ext_vector_type(8)));

__device__ __forceinline__ short bf16rne(float f) {
    uint32_t x = __builtin_bit_cast(uint32_t, f);
    return (short)((x + 0x7FFFu + ((x >> 16) & 1u)) >> 16);
}

__device__ __forceinline__ float fast_tanh(float x) {
    float e = __expf(2.0f * x);
    return 1.0f - 2.0f * __builtin_amdgcn_rcpf(e + 1.0f);
}

// Barrier that orders LDS only (lgkmcnt); global loads stay in flight (R6-proven correct).
__device__ __forceinline__ void wg_barrier_lds() {
    asm volatile("s_waitcnt lgkmcnt(0)" ::: "memory");
    __builtin_amdgcn_sched_barrier(0);
    __builtin_amdgcn_s_barrier();
    __builtin_amdgcn_sched_barrier(0);
}

// ---- fused prep: blocks 0-255 convert W2 -> w2t[u][h] bf16; blocks 256-319 qproj ----
__global__ __launch_bounds__(256) void k_prep(const float* __restrict__ W2,
                                              uint16_t* __restrict__ w2t,
                                              const float* __restrict__ query,
                                              const float* __restrict__ W1,
                                              const float* __restrict__ b1,
                                              const float* __restrict__ b2,
                                              float* __restrict__ qpc) {
    if (blockIdx.x < 256) {
        int idx = blockIdx.x * 256 + threadIdx.x;
        int h = idx >> 8;
        int u = idx & 255;
        w2t[u * 256 + h] = (uint16_t)bf16rne(W2[idx]);
    } else {
        __shared__ float qrow[H_];
        int b = blockIdx.x - 256, u = threadIdx.x;
        qrow[u] = query[b * H_ + u];
        __syncthreads();
        float acc = b1[u] + b2[u];
#pragma unroll 8
        for (int h = 0; h < H_; ++h) acc += qrow[h] * W1[h * U_ + u];
        qpc[b * U_ + u] = acc;
    }
}

// ---------------- fused main: R11 body EXACTLY (92.65us best) + fused finish ----------
// Only addition vs R11: last-WG-per-b finish (threadfence + atomicAdd; the 16th WG of
// each b reduces the 16 partials and writes ctx + normalized weights), eliminating the
// k_fin launch.  Output deterministic: summation order fixed regardless of finisher.
#define TR 32
#define NT 8
__global__ __launch_bounds__(512, 2) void k_main(const float* __restrict__ values,
                                                 const uint16_t* __restrict__ w2t,
                                                 const float* __restrict__ qpc,
                                                 const float* __restrict__ V,
                                                 float* __restrict__ score,
                                                 float* __restrict__ part_O,
                                                 float* __restrict__ part_s,
                                                 int* __restrict__ cnt,
                                                 float* __restrict__ ctx,
                                                 float* __restrict__ weights) {
    __shared__ __align__(16) char Ab[TR * 512];   // bf16 [32][256], byte ^= ((row&7)<<4)
    __shared__ float red[TR][9];                  // per-row partials from 8 waves
    __shared__ float Ored[TR][16][16];            // per-thread context partials (32 KB)
    __shared__ float sred[TR];
    __shared__ int lastflag;

    const int tid = threadIdx.x;
    const int wg = blockIdx.x;          // 0..1023
    const int b = wg >> 4;
    const int chunk = (wg & 15) * (NT * TR);

    const int w = tid >> 6;             // wave 0..7
    const int l = tid & 63;
    const int c = l & 15;
    const int g = l >> 4;

    // A fragments (W2) in regs for whole kernel: 2 strips x 8 ks (64 VGPR)
    short8 afr[2][8];
#pragma unroll
    for (int s = 0; s < 2; ++s) {
        const uint16_t* ap = w2t + (size_t)(w * 32 + s * 16 + c) * 256 + g * 8;
#pragma unroll
        for (int ks = 0; ks < 8; ++ks) afr[s][ks] = *(const short8*)(ap + ks * 32);
    }
    float qv[2][4], vv[2][4];
#pragma unroll
    for (int s = 0; s < 2; ++s)
#pragma unroll
        for (int r = 0; r < 4; ++r) {
            int u = w * 32 + s * 16 + g * 4 + r;
            qv[s][r] = qpc[b * U_ + u];
            vv[s][r] = V[u];
        }

    const float* vbase = values + (size_t)b * T_ * H_;
    const int srow = tid >> 4;          // 0..31: row this thread stages/consumes
    const int q = tid & 15;             // 16B chunk within row
    const int sswz = (srow & 7) << 4;
    char* wr0 = Ab + srow * 512 + ((q * 16) ^ sswz);
    char* wr1 = Ab + srow * 512 + ((q * 16 + 256) ^ sswz);
    const float* sbase = vbase + (size_t)srow * H_ + q * 8;

    // single time-shared value slot (16 VGPR) + fp32 ctx accumulators
    f32x4 vt0, vt1, vt2, vt3;
    float Oacc[16];
#pragma unroll
    for (int j = 0; j < 16; ++j) Oacc[j] = 0.f;
    float sacc = 0.f;

    {   // prologue: load tile 0 (HBM)
        const float* nb = sbase + (size_t)chunk * H_;
        vt0 = *(const f32x4*)(nb);       vt1 = *(const f32x4*)(nb + 4);
        vt2 = *(const f32x4*)(nb + 128); vt3 = *(const f32x4*)(nb + 132);
    }

#pragma unroll
    for (int t = 0; t < NT; ++t) {
        wg_barrier_lds();               // B1: red(t-1) ready; Ab readers done
        {   // stage tile t (in vt) -> bf16 swizzled LDS
            short8 s0, s1;
            s0[0] = bf16rne(vt0[0]); s0[1] = bf16rne(vt0[1]);
            s0[2] = bf16rne(vt0[2]); s0[3] = bf16rne(vt0[3]);
            s0[4] = bf16rne(vt1[0]); s0[5] = bf16rne(vt1[1]);
            s0[6] = bf16rne(vt1[2]); s0[7] = bf16rne(vt1[3]);
            s1[0] = bf16rne(vt2[0]); s1[1] = bf16rne(vt2[1]);
            s1[2] = bf16rne(vt2[2]); s1[3] = bf16rne(vt2[3]);
            s1[4] = bf16rne(vt3[0]); s1[5] = bf16rne(vt3[1]);
            s1[6] = bf16rne(vt3[2]); s1[7] = bf16rne(vt3[3]);
            *(short8*)wr0 = s0;
            *(short8*)wr1 = s1;
        }
        // consume tile t-1: re-read fp32 from L2/L3 into the freed vt slot
        if (t > 0) {
            const float* rb = sbase + (size_t)(chunk + (t - 1) * TR) * H_;
            vt0 = *(const f32x4*)(rb);       vt1 = *(const f32x4*)(rb + 4);
            vt2 = *(const f32x4*)(rb + 128); vt3 = *(const f32x4*)(rb + 132);
            float ssum = 0.f;
#pragma unroll
            for (int j = 0; j < 8; ++j) ssum += red[srow][j];
            float wgt = __expf(ssum);
            if (q == 0) {
                sacc += wgt;
                score[(size_t)b * T_ + chunk + (t - 1) * TR + srow] = ssum;
            }
#pragma unroll
            for (int j = 0; j < 4; ++j) {
                Oacc[j]      += wgt * vt0[j];
                Oacc[4 + j]  += wgt * vt1[j];
                Oacc[8 + j]  += wgt * vt2[j];
                Oacc[12 + j] += wgt * vt3[j];
            }
        }
        // prefetch tile t+1 (HBM) into vt; rides through B2 (lgkm-only barrier)
        if (t + 1 < NT) {
            const float* nb = sbase + (size_t)(chunk + (t + 1) * TR) * H_;
            vt0 = *(const f32x4*)(nb);       vt1 = *(const f32x4*)(nb + 4);
            vt2 = *(const f32x4*)(nb + 128); vt3 = *(const f32x4*)(nb + 132);
        }
        wg_barrier_lds();               // B2: Ab(t) staged
        // MFMA phase on tile t
#pragma unroll
        for (int sub = 0; sub < 2; ++sub) {
            const char* rp = Ab + (sub * 16 + c) * 512;
            const int swz = (c & 7) << 4;
            f32x4 acc0 = (f32x4)(0.0f);
            f32x4 acc1 = (f32x4)(0.0f);
#pragma unroll
            for (int ks = 0; ks < 8; ++ks) {
                short8 bf = *(const short8*)(rp + ((ks * 64 + g * 16) ^ swz));
                acc0 = __builtin_amdgcn_mfma_f32_16x16x32_bf16(afr[0][ks], bf, acc0, 0, 0, 0);
                acc1 = __builtin_amdgcn_mfma_f32_16x16x32_bf16(afr[1][ks], bf, acc1, 0, 0, 0);
            }
            float p = 0.f;
#pragma unroll
            for (int r = 0; r < 4; ++r) {
                p += fast_tanh(acc0[r] + qv[0][r]) * vv[0][r];
                p += fast_tanh(acc1[r] + qv[1][r]) * vv[1][r];
            }
            p += __shfl_xor(p, 16, 64);
            p += __shfl_xor(p, 32, 64);
            if (g == 0) red[sub * 16 + c][w] = p;
        }
    }
    __syncthreads();
    {   // final consume: tile NT-1, re-read from L2
        const float* rb = sbase + (size_t)(chunk + (NT - 1) * TR) * H_;
        vt0 = *(const f32x4*)(rb);       vt1 = *(const f32x4*)(rb + 4);
        vt2 = *(const f32x4*)(rb + 128); vt3 = *(const f32x4*)(rb + 132);
        float ssum = 0.f;
#pragma unroll
        for (int j = 0; j < 8; ++j) ssum += red[srow][j];
        float wgt = __expf(ssum);
        if (q == 0) {
            sacc += wgt;
            score[(size_t)b * T_ + chunk + (NT - 1) * TR + srow] = ssum;
        }
#pragma unroll
        for (int j = 0; j < 4; ++j) {
            Oacc[j]      += wgt * vt0[j];
            Oacc[4 + j]  += wgt * vt1[j];
            Oacc[8 + j]  += wgt * vt2[j];
            Oacc[12 + j] += wgt * vt3[j];
        }
    }
    // reduce per-thread context partials across the 32 rows
#pragma unroll
    for (int j = 0; j < 16; ++j) Ored[srow][q][j] = Oacc[j];
    if (q == 0) sred[srow] = sacc;
    __syncthreads();
    if (tid < 256) {
        int col = tid;
        int qq, jj;
        if (col < 128) { qq = col >> 3; jj = col & 7; }
        else           { qq = (col - 128) >> 3; jj = 8 + (col & 7); }
        float o = 0.f;
#pragma unroll
        for (int s = 0; s < TR; ++s) o += Ored[s][qq][jj];
        part_O[(size_t)wg * 256 + col] = o;
    }
    if (tid == 0) {
        float sb = 0.f;
#pragma unroll
        for (int s = 0; s < TR; ++s) sb += sred[s];
        part_s[wg] = sb;
    }

    // ---- fused finish: the 16th (last) WG of this b reduces partials ----
    __threadfence();                    // release: partial writes visible device-wide
    __syncthreads();
    if (tid == 0) lastflag = (atomicAdd(&cnt[b], 1) == 15);
    __syncthreads();
    if (lastflag) {
        __threadfence();                // acquire: see other WGs' partials
        float sb = 0.f;
#pragma unroll
        for (int ch = 0; ch < 16; ++ch) sb += part_s[b * 16 + ch];
        float inv = 1.0f / sb;
        if (tid < 256) {
            float o = 0.f;
#pragma unroll
            for (int ch = 0; ch < 16; ++ch) o += part_O[(size_t)(b * 16 + ch) * 256 + tid];
            ctx[b * H_ + tid] = o * inv;
        }
#pragma unroll
        for (int i = 0; i < 8; ++i) {
            int idx = i * 512 + tid;
            float s = score[(size_t)b * T_ + idx];
            weights[(size_t)b * T_ + idx] = __expf(s) * inv;
        }
    }
}

extern "C" void kernel_launch(void* const* d_in, const int* in_sizes, int n_in,
                              void* d_out, int out_size, void* d_ws, size_t ws_size,
                              hipStream_t stream) {
    const float* query  = (const float*)d_in[0];
    const float* values = (const float*)d_in[1];
    const float* W1     = (const float*)d_in[2];
    const float* b1     = (const float*)d_in[3];
    const float* W2     = (const float*)d_in[4];
    const float* b2     = (const float*)d_in[5];
    const float* V      = (const float*)d_in[6];
    // d_in[7] = bV: softmax is shift-invariant -> no effect on outputs.

    float* out = (float*)d_out;
    float* ctx = out;                    // [B,H]
    float* weights = out + B_ * H_;      // [B,T,1]

    char* ws = (char*)d_ws;
    uint16_t* w2t   = (uint16_t*)ws;                               // 128 KB
    float* qpc      = (float*)(ws + 131072);                       // 64 KB
    float* scorebuf = (float*)(ws + 196608);                       // 1 MB
    float* part_O   = (float*)(ws + 1245184);                      // 1 MB
    float* part_s   = (float*)(ws + 2293760);                      // 4 KB
    int*   cnt      = (int*)  (ws + 2297856);                      // 256 B

    hipMemsetAsync(cnt, 0, 64 * sizeof(int), stream);
    k_prep<<<dim3(320), dim3(256), 0, stream>>>(W2, w2t, query, W1, b1, b2, qpc);
    k_main<<<dim3(1024), dim3(512), 0, stream>>>(values, w2t, qpc, V, scorebuf,
                                                 part_O, part_s, cnt, ctx, weights);
}

// Round 16
// 92.648 us; speedup vs baseline: 4.2142x; 4.2142x over previous
//
#include <hip/hip_runtime.h>
#include <stdint.h>

#define B_ 64
#define T_ 4096
#define H_ 256
#define U_ 256

typedef float f32x4 __attribute__((ext_vector_type(4)));
typedef short short8 __attribute__((ext_vector_type(8)));

__device__ __forceinline__ short bf16rne(float f) {
    uint32_t x = __builtin_bit_cast(uint32_t, f);
    return (short)((x + 0x7FFFu + ((x >> 16) & 1u)) >> 16);
}

__device__ __forceinline__ float fast_tanh(float x) {
    float e = __expf(2.0f * x);
    return 1.0f - 2.0f * __builtin_amdgcn_rcpf(e + 1.0f);
}

// Barrier that orders LDS only (lgkmcnt); global loads stay in flight (R6-proven correct).
__device__ __forceinline__ void wg_barrier_lds() {
    asm volatile("s_waitcnt lgkmcnt(0)" ::: "memory");
    __builtin_amdgcn_sched_barrier(0);
    __builtin_amdgcn_s_barrier();
    __builtin_amdgcn_sched_barrier(0);
}

// ---- fused prep: blocks 0-255 convert W2 -> w2t[u][h] bf16; blocks 256-319 qproj ----
__global__ __launch_bounds__(256) void k_prep(const float* __restrict__ W2,
                                              uint16_t* __restrict__ w2t,
                                              const float* __restrict__ query,
                                              const float* __restrict__ W1,
                                              const float* __restrict__ b1,
                                              const float* __restrict__ b2,
                                              float* __restrict__ qpc) {
    if (blockIdx.x < 256) {
        int idx = blockIdx.x * 256 + threadIdx.x;
        int h = idx >> 8;
        int u = idx & 255;
        w2t[u * 256 + h] = (uint16_t)bf16rne(W2[idx]);
    } else {
        __shared__ float qrow[H_];
        int b = blockIdx.x - 256, u = threadIdx.x;
        qrow[u] = query[b * H_ + u];
        __syncthreads();
        float acc = b1[u] + b2[u];
#pragma unroll 8
        for (int h = 0; h < H_; ++h) acc += qrow[h] * W1[h * U_ + u];
        qpc[b * U_ + u] = acc;
    }
}

// ---------------- fused main: 512 thr / 8 waves, 2 WGs/CU (R11, 92.65us, BEST) --------
// Best-of-session configuration, restored verbatim.  vt is ONE 16-reg slot time-shared:
// stage tile t -> re-read tile t-1 from L2 (fp32 ctx accum) -> prefetch tile t+1.
// Two lgkm-only barriers per tile; ~124-VGPR state under (512,2)'s 128 cap.
#define TR 32
#define NT 8
__global__ __launch_bounds__(512, 2) void k_main(const float* __restrict__ values,
                                                 const uint16_t* __restrict__ w2t,
                                                 const float* __restrict__ qpc,
                                                 const float* __restrict__ V,
                                                 float* __restrict__ score,
                                                 float* __restrict__ part_O,
                                                 float* __restrict__ part_s) {
    __shared__ __align__(16) char Ab[TR * 512];   // bf16 [32][256], byte ^= ((row&7)<<4)
    __shared__ float red[TR][9];                  // per-row partials from 8 waves
    __shared__ float Ored[TR][16][16];            // per-thread context partials (32 KB)
    __shared__ float sred[TR];

    const int tid = threadIdx.x;
    const int wg = blockIdx.x;          // 0..1023
    const int b = wg >> 4;
    const int chunk = (wg & 15) * (NT * TR);

    const int w = tid >> 6;             // wave 0..7
    const int l = tid & 63;
    const int c = l & 15;
    const int g = l >> 4;

    // A fragments (W2) in regs for whole kernel: 2 strips x 8 ks (64 VGPR)
    short8 afr[2][8];
#pragma unroll
    for (int s = 0; s < 2; ++s) {
        const uint16_t* ap = w2t + (size_t)(w * 32 + s * 16 + c) * 256 + g * 8;
#pragma unroll
        for (int ks = 0; ks < 8; ++ks) afr[s][ks] = *(const short8*)(ap + ks * 32);
    }
    float qv[2][4], vv[2][4];
#pragma unroll
    for (int s = 0; s < 2; ++s)
#pragma unroll
        for (int r = 0; r < 4; ++r) {
            int u = w * 32 + s * 16 + g * 4 + r;
            qv[s][r] = qpc[b * U_ + u];
            vv[s][r] = V[u];
        }

    const float* vbase = values + (size_t)b * T_ * H_;
    const int srow = tid >> 4;          // 0..31: row this thread stages/consumes
    const int q = tid & 15;             // 16B chunk within row
    const int sswz = (srow & 7) << 4;
    char* wr0 = Ab + srow * 512 + ((q * 16) ^ sswz);
    char* wr1 = Ab + srow * 512 + ((q * 16 + 256) ^ sswz);
    const float* sbase = vbase + (size_t)srow * H_ + q * 8;

    // single time-shared value slot (16 VGPR) + fp32 ctx accumulators
    f32x4 vt0, vt1, vt2, vt3;
    float Oacc[16];
#pragma unroll
    for (int j = 0; j < 16; ++j) Oacc[j] = 0.f;
    float sacc = 0.f;

    {   // prologue: load tile 0 (HBM)
        const float* nb = sbase + (size_t)chunk * H_;
        vt0 = *(const f32x4*)(nb);       vt1 = *(const f32x4*)(nb + 4);
        vt2 = *(const f32x4*)(nb + 128); vt3 = *(const f32x4*)(nb + 132);
    }

#pragma unroll
    for (int t = 0; t < NT; ++t) {
        wg_barrier_lds();               // B1: red(t-1) ready; Ab readers done
        {   // stage tile t (in vt) -> bf16 swizzled LDS
            short8 s0, s1;
            s0[0] = bf16rne(vt0[0]); s0[1] = bf16rne(vt0[1]);
            s0[2] = bf16rne(vt0[2]); s0[3] = bf16rne(vt0[3]);
            s0[4] = bf16rne(vt1[0]); s0[5] = bf16rne(vt1[1]);
            s0[6] = bf16rne(vt1[2]); s0[7] = bf16rne(vt1[3]);
            s1[0] = bf16rne(vt2[0]); s1[1] = bf16rne(vt2[1]);
            s1[2] = bf16rne(vt2[2]); s1[3] = bf16rne(vt2[3]);
            s1[4] = bf16rne(vt3[0]); s1[5] = bf16rne(vt3[1]);
            s1[6] = bf16rne(vt3[2]); s1[7] = bf16rne(vt3[3]);
            *(short8*)wr0 = s0;
            *(short8*)wr1 = s1;
        }
        // consume tile t-1: re-read fp32 from L2/L3 into the freed vt slot
        if (t > 0) {
            const float* rb = sbase + (size_t)(chunk + (t - 1) * TR) * H_;
            vt0 = *(const f32x4*)(rb);       vt1 = *(const f32x4*)(rb + 4);
            vt2 = *(const f32x4*)(rb + 128); vt3 = *(const f32x4*)(rb + 132);
            float ssum = 0.f;
#pragma unroll
            for (int j = 0; j < 8; ++j) ssum += red[srow][j];
            float wgt = __expf(ssum);
            if (q == 0) {
                sacc += wgt;
                score[(size_t)b * T_ + chunk + (t - 1) * TR + srow] = ssum;
            }
#pragma unroll
            for (int j = 0; j < 4; ++j) {
                Oacc[j]      += wgt * vt0[j];
                Oacc[4 + j]  += wgt * vt1[j];
                Oacc[8 + j]  += wgt * vt2[j];
                Oacc[12 + j] += wgt * vt3[j];
            }
        }
        // prefetch tile t+1 (HBM) into vt; rides through B2 (lgkm-only barrier)
        if (t + 1 < NT) {
            const float* nb = sbase + (size_t)(chunk + (t + 1) * TR) * H_;
            vt0 = *(const f32x4*)(nb);       vt1 = *(const f32x4*)(nb + 4);
            vt2 = *(const f32x4*)(nb + 128); vt3 = *(const f32x4*)(nb + 132);
        }
        wg_barrier_lds();               // B2: Ab(t) staged
        // MFMA phase on tile t
#pragma unroll
        for (int sub = 0; sub < 2; ++sub) {
            const char* rp = Ab + (sub * 16 + c) * 512;
            const int swz = (c & 7) << 4;
            f32x4 acc0 = (f32x4)(0.0f);
            f32x4 acc1 = (f32x4)(0.0f);
#pragma unroll
            for (int ks = 0; ks < 8; ++ks) {
                short8 bf = *(const short8*)(rp + ((ks * 64 + g * 16) ^ swz));
                acc0 = __builtin_amdgcn_mfma_f32_16x16x32_bf16(afr[0][ks], bf, acc0, 0, 0, 0);
                acc1 = __builtin_amdgcn_mfma_f32_16x16x32_bf16(afr[1][ks], bf, acc1, 0, 0, 0);
            }
            float p = 0.f;
#pragma unroll
            for (int r = 0; r < 4; ++r) {
                p += fast_tanh(acc0[r] + qv[0][r]) * vv[0][r];
                p += fast_tanh(acc1[r] + qv[1][r]) * vv[1][r];
            }
            p += __shfl_xor(p, 16, 64);
            p += __shfl_xor(p, 32, 64);
            if (g == 0) red[sub * 16 + c][w] = p;
        }
    }
    __syncthreads();
    {   // final consume: tile NT-1, re-read from L2
        const float* rb = sbase + (size_t)(chunk + (NT - 1) * TR) * H_;
        vt0 = *(const f32x4*)(rb);       vt1 = *(const f32x4*)(rb + 4);
        vt2 = *(const f32x4*)(rb + 128); vt3 = *(const f32x4*)(rb + 132);
        float ssum = 0.f;
#pragma unroll
        for (int j = 0; j < 8; ++j) ssum += red[srow][j];
        float wgt = __expf(ssum);
        if (q == 0) {
            sacc += wgt;
            score[(size_t)b * T_ + chunk + (NT - 1) * TR + srow] = ssum;
        }
#pragma unroll
        for (int j = 0; j < 4; ++j) {
            Oacc[j]      += wgt * vt0[j];
            Oacc[4 + j]  += wgt * vt1[j];
            Oacc[8 + j]  += wgt * vt2[j];
            Oacc[12 + j] += wgt * vt3[j];
        }
    }
    // reduce per-thread context partials across the 32 rows
#pragma unroll
    for (int j = 0; j < 16; ++j) Ored[srow][q][j] = Oacc[j];
    if (q == 0) sred[srow] = sacc;
    __syncthreads();
    if (tid < 256) {
        int col = tid;
        int qq, jj;
        if (col < 128) { qq = col >> 3; jj = col & 7; }
        else           { qq = (col - 128) >> 3; jj = 8 + (col & 7); }
        float o = 0.f;
#pragma unroll
        for (int s = 0; s < TR; ++s) o += Ored[s][qq][jj];
        part_O[(size_t)wg * 256 + col] = o;
    }
    if (tid == 0) {
        float sb = 0.f;
#pragma unroll
        for (int s = 0; s < TR; ++s) sb += sred[s];
        part_s[wg] = sb;
    }
}

// ---------------- finish: reduce partials, write ctx + normalized weights ----------------
__global__ __launch_bounds__(256) void k_fin(const float* __restrict__ part_O,
                                             const float* __restrict__ part_s,
                                             const float* __restrict__ score,
                                             float* __restrict__ ctx,
                                             float* __restrict__ weights) {
    int b = blockIdx.x >> 3;
    int j = blockIdx.x & 7;
    int col = threadIdx.x;
    float sb = 0.f;
#pragma unroll
    for (int ch = 0; ch < 16; ++ch) sb += part_s[b * 16 + ch];
    float inv = 1.0f / sb;
    if (j == 0) {
        float o = 0.f;
#pragma unroll
        for (int ch = 0; ch < 16; ++ch) o += part_O[(size_t)(b * 16 + ch) * 256 + col];
        ctx[b * H_ + col] = o * inv;
    }
#pragma unroll
    for (int i = 0; i < 2; ++i) {
        int idx = j * 512 + i * 256 + col;
        float s = score[(size_t)b * T_ + idx];
        weights[(size_t)b * T_ + idx] = __expf(s) * inv;
    }
}

extern "C" void kernel_launch(void* const* d_in, const int* in_sizes, int n_in,
                              void* d_out, int out_size, void* d_ws, size_t ws_size,
                              hipStream_t stream) {
    const float* query  = (const float*)d_in[0];
    const float* values = (const float*)d_in[1];
    const float* W1     = (const float*)d_in[2];
    const float* b1     = (const float*)d_in[3];
    const float* W2     = (const float*)d_in[4];
    const float* b2     = (const float*)d_in[5];
    const float* V      = (const float*)d_in[6];
    // d_in[7] = bV: softmax is shift-invariant -> no effect on outputs.

    float* out = (float*)d_out;
    float* ctx = out;                    // [B,H]
    float* weights = out + B_ * H_;      // [B,T,1]

    char* ws = (char*)d_ws;
    uint16_t* w2t   = (uint16_t*)ws;                               // 128 KB
    float* qpc      = (float*)(ws + 131072);                       // 64 KB
    float* scorebuf = (float*)(ws + 131072 + 65536);               // 1 MB
    float* part_O   = (float*)(ws + 131072 + 65536 + 1048576);     // 1 MB
    float* part_s   = (float*)(ws + 131072 + 65536 + 2097152);     // 4 KB

    k_prep<<<dim3(320), dim3(256), 0, stream>>>(W2, w2t, query, W1, b1, b2, qpc);
    k_main<<<dim3(1024), dim3(512), 0, stream>>>(values, w2t, qpc, V, scorebuf,
                                                 part_O, part_s);
    k_fin<<<dim3(512), dim3(256), 0, stream>>>(part_O, part_s, scorebuf, ctx, weights);
}